// Round 4
// baseline (484.971 us; speedup 1.0000x reference)
//
#include <hip/hip_runtime.h>

#define NA 50     // agents
#define SP 132    // padded LDS row stride for 128-wide feature rows (bank-spread + 16B aligned)
#define ASP 52    // padded stride for 50-wide attention rows

// C(50x128, LDS) = A(50x128, LDS stride SP) @ W(128x128, global) [+ bias]
// Thread map: tx = tid&15 -> 8 cols (tx*8..+7); ty = tid>>4 -> rows ty, ty+16, ty+32 (+ ty+48 if ty<2)
template <bool HAS_BIAS>
__device__ __forceinline__ void mm_AxW(const float* __restrict__ A,
                                       const float* __restrict__ W,
                                       const float* __restrict__ bias,
                                       float* __restrict__ C,
                                       int tx, int ty)
{
    const int r0 = ty, r1 = ty + 16, r2 = ty + 32;
    const bool has3 = (ty < 2);
    const int r3 = has3 ? (ty + 48) : ty;   // safe duplicate read when absent
    const int c0 = tx * 8;
    float acc0[8], acc1[8], acc2[8], acc3[8];
    #pragma unroll
    for (int j = 0; j < 8; ++j) { acc0[j] = 0.f; acc1[j] = 0.f; acc2[j] = 0.f; acc3[j] = 0.f; }

    for (int k = 0; k < 128; ++k) {
        const float a0 = A[r0 * SP + k];
        const float a1 = A[r1 * SP + k];
        const float a2 = A[r2 * SP + k];
        const float a3 = A[r3 * SP + k];
        const float4 w0 = *reinterpret_cast<const float4*>(W + k * 128 + c0);
        const float4 w1 = *reinterpret_cast<const float4*>(W + k * 128 + c0 + 4);
        const float w[8] = {w0.x, w0.y, w0.z, w0.w, w1.x, w1.y, w1.z, w1.w};
        #pragma unroll
        for (int j = 0; j < 8; ++j) {
            acc0[j] = fmaf(a0, w[j], acc0[j]);
            acc1[j] = fmaf(a1, w[j], acc1[j]);
            acc2[j] = fmaf(a2, w[j], acc2[j]);
            acc3[j] = fmaf(a3, w[j], acc3[j]);
        }
    }
    #pragma unroll
    for (int j = 0; j < 8; ++j) {
        const float bb = HAS_BIAS ? bias[c0 + j] : 0.f;
        C[r0 * SP + c0 + j] = acc0[j] + bb;
        C[r1 * SP + c0 + j] = acc1[j] + bb;
        C[r2 * SP + c0 + j] = acc2[j] + bb;
        if (has3) C[r3 * SP + c0 + j] = acc3[j] + bb;
    }
}

__global__ __launch_bounds__(256, 2) void gnn_fused(
    const float* __restrict__ x,
    const float* __restrict__ W1, const float* __restrict__ b1,
    const float* __restrict__ W2, const float* __restrict__ b2,
    const float* __restrict__ Wg,
    const float* __restrict__ a1v, const float* __restrict__ a2v,
    const float* __restrict__ Wo1, const float* __restrict__ bo1,
    const float* __restrict__ Wo2, const float* __restrict__ bo2,
    float* __restrict__ out)
{
    __shared__ float nf[NA * SP];        // 26400 B
    __shared__ float hbuf[NA * SP];      // 26400 B
    __shared__ float pool[NA * ASP];     // 10400 B: curs(300) -> attn(50x52) -> hid2(512), time-aliased
    __shared__ float s1[NA], s2[NA];     // 400 B   (total 63.6 KB -> 2 blocks/CU)

    float* const curs = pool;   // [50][6]
    float* const attn = pool;   // [50][ASP]
    float* const hid2 = pool;   // [512]

    const int tid = threadIdx.x;
    const int b = blockIdx.x;
    const int tx = tid & 15;
    const int ty = tid >> 4;

    // ---- 1. load cur = x[b, :, T-1, :]  (only 300 of 33000 floats per batch elem) ----
    for (int idx = tid; idx < NA * 6; idx += 256) {
        const int a = idx / 6;
        const int f = idx - a * 6;
        curs[idx] = x[(size_t)b * 33000 + a * 660 + 109 * 6 + f];
    }
    __syncthreads();

    // ---- 2. hidden = relu(cur @ W1 + b1) -> hbuf ----
    for (int idx = tid; idx < NA * 128; idx += 256) {
        const int i = idx >> 7;
        const int j = idx & 127;
        float acc = b1[j];
        #pragma unroll
        for (int k = 0; k < 6; ++k) acc = fmaf(curs[i * 6 + k], W1[k * 128 + j], acc);
        hbuf[i * SP + j] = fmaxf(acc, 0.f);
    }
    __syncthreads();

    // ---- 3. nf = hidden @ W2 + b2 ----
    mm_AxW<true>(hbuf, W2, b2, nf, tx, ty);
    __syncthreads();

    // ---- 4. three GAT layers ----
    for (int l = 0; l < 3; ++l) {
        // h = nf @ Wg[l]
        mm_AxW<false>(nf, Wg + l * 128 * 128, nullptr, hbuf, tx, ty);
        __syncthreads();

        // s1[i] = h[i]·a1[l], s2[i] = h[i]·a2[l]  (two waves, one row per lane)
        if (tid < NA) {
            const float* av = a1v + l * 128;
            float acc = 0.f;
            for (int k = 0; k < 128; ++k) acc = fmaf(hbuf[tid * SP + k], av[k], acc);
            s1[tid] = acc;
        } else if (tid >= 64 && tid < 64 + NA) {
            const int i = tid - 64;
            const float* av = a2v + l * 128;
            float acc = 0.f;
            for (int k = 0; k < 128; ++k) acc = fmaf(hbuf[i * SP + k], av[k], acc);
            s2[i] = acc;
        }
        __syncthreads();

        // attn[i][:] = softmax_j( leaky_relu(s1[i]+s2[j], 0.2), j != i ), diag = 0
        // 4 lanes per row, shfl_xor group-reduce (no serial-lane softmax)
        {
            const int row = tid >> 2;
            const int g = tid & 3;
            const bool active = (row < NA) && (l < 2 || row == 0); // last layer: only row 0 consumed
            float pv[13];
            float m = -1e30f;
            if (active) {
                const float si = s1[row];
                #pragma unroll
                for (int jj = 0; jj < 13; ++jj) {
                    const int j = g + jj * 4;
                    float e = -1e30f;
                    if (j < NA && j != row) {
                        const float v = si + s2[j];
                        e = (v > 0.f) ? v : 0.2f * v;
                    }
                    pv[jj] = e;
                    m = fmaxf(m, e);
                }
            }
            m = fmaxf(m, __shfl_xor(m, 1));
            m = fmaxf(m, __shfl_xor(m, 2));
            float ssum = 0.f;
            if (active) {
                #pragma unroll
                for (int jj = 0; jj < 13; ++jj) {
                    const int j = g + jj * 4;
                    const float p = (j < NA && j != row) ? __expf(pv[jj] - m) : 0.f;
                    pv[jj] = p;
                    ssum += p;
                }
            }
            ssum += __shfl_xor(ssum, 1);
            ssum += __shfl_xor(ssum, 2);
            if (active) {
                const float inv = 1.f / ssum;
                #pragma unroll
                for (int jj = 0; jj < 13; ++jj) {
                    const int j = g + jj * 4;
                    if (j < NA) attn[row * ASP + j] = pv[jj] * inv;  // diag gets exact 0
                }
            }
        }
        __syncthreads();

        // nf = attn @ h   (K = 50, from LDS; last layer: only row 0)
        {
            const bool last = (l == 2);
            const int r0 = ty, r1 = ty + 16, r2 = ty + 32;
            const bool has3 = (ty < 2);
            const int r3 = has3 ? (ty + 48) : ty;
            const int c0 = tx * 8;
            float acc0[8], acc1[8], acc2[8], acc3[8];
            #pragma unroll
            for (int j = 0; j < 8; ++j) { acc0[j] = 0.f; acc1[j] = 0.f; acc2[j] = 0.f; acc3[j] = 0.f; }
            if (!last || ty == 0) {
                for (int k = 0; k < NA; ++k) {
                    const float4 w0 = *reinterpret_cast<const float4*>(&hbuf[k * SP + c0]);
                    const float4 w1 = *reinterpret_cast<const float4*>(&hbuf[k * SP + c0 + 4]);
                    const float a0 = attn[r0 * ASP + k];
                    const float a1 = attn[r1 * ASP + k];
                    const float a2 = attn[r2 * ASP + k];
                    const float a3 = attn[r3 * ASP + k];
                    const float w[8] = {w0.x, w0.y, w0.z, w0.w, w1.x, w1.y, w1.z, w1.w};
                    #pragma unroll
                    for (int j = 0; j < 8; ++j) {
                        acc0[j] = fmaf(a0, w[j], acc0[j]);
                        acc1[j] = fmaf(a1, w[j], acc1[j]);
                        acc2[j] = fmaf(a2, w[j], acc2[j]);
                        acc3[j] = fmaf(a3, w[j], acc3[j]);
                    }
                }
            }
            // no barrier needed before writes: nf has no concurrent readers in this phase
            if (!last) {
                #pragma unroll
                for (int j = 0; j < 8; ++j) {
                    nf[r0 * SP + c0 + j] = acc0[j];
                    nf[r1 * SP + c0 + j] = acc1[j];
                    nf[r2 * SP + c0 + j] = acc2[j];
                    if (has3) nf[r3 * SP + c0 + j] = acc3[j];
                }
            } else if (ty == 0) {
                #pragma unroll
                for (int j = 0; j < 8; ++j) nf[c0 + j] = acc0[j];
            }
        }
        __syncthreads();
    }

    // ---- 5. output MLP on ego = nf[0][0..127] ----
    // hid2 aliases the attn pool: attn's last read was before the barrier above.
    float h2[2];
    #pragma unroll
    for (int u = 0; u < 2; ++u) {
        const int o = tid + u * 256;
        float acc = bo1[o];
        for (int k = 0; k < 128; ++k) acc = fmaf(nf[k], Wo1[k * 512 + o], acc);
        h2[u] = fmaxf(acc, 0.f);
    }
    __syncthreads();   // attn pool fully consumed; safe to overwrite as hid2
    hid2[tid] = h2[0];
    hid2[tid + 256] = h2[1];
    __syncthreads();

    if (tid < 120) {
        float acc = bo2[tid];
        for (int o = 0; o < 512; ++o) acc = fmaf(hid2[o], Wo2[o * 120 + tid], acc);
        out[b * 120 + tid] = acc;   // (B,60,2) flat
    }
}

extern "C" void kernel_launch(void* const* d_in, const int* in_sizes, int n_in,
                              void* d_out, int out_size, void* d_ws, size_t ws_size,
                              hipStream_t stream) {
    const float* x   = (const float*)d_in[0];
    const float* W1  = (const float*)d_in[1];
    const float* b1  = (const float*)d_in[2];
    const float* W2  = (const float*)d_in[3];
    const float* b2  = (const float*)d_in[4];
    // d_in[5..8] = We1, be1, We2, be2 : dead code in the reference (ef is deleted) — unused
    const float* Wg  = (const float*)d_in[9];
    const float* a1  = (const float*)d_in[10];
    const float* a2  = (const float*)d_in[11];
    const float* Wo1 = (const float*)d_in[12];
    const float* bo1 = (const float*)d_in[13];
    const float* Wo2 = (const float*)d_in[14];
    const float* bo2 = (const float*)d_in[15];

    const int B = in_sizes[0] / (50 * 110 * 6);   // 1024
    gnn_fused<<<B, 256, 0, stream>>>(x, W1, b1, W2, b2, Wg, a1, a2,
                                     Wo1, bo1, Wo2, bo2, (float*)d_out);
}

// Round 6
// 402.856 us; speedup vs baseline: 1.2038x; 1.2038x over previous
//
#include <hip/hip_runtime.h>

#define NA 50     // agents
#define SP 132    // padded LDS row stride, %4==0 so float4 LDS loads stay 16B-aligned
#define ASP 52    // attention row stride, %4==0

// C(50x128, LDS) = A(50x128, LDS) @ W(128x128, global).
// FUSED_SCORES: no bias, and computes s1[r]=C_row·av1, s2[r]=C_row·av2 in-register
// (shfl_xor reduce over the 16 tx lanes) — replaces a whole barrier-phase.
// Thread map: tx=tid&15 -> 8 cols; ty=tid>>4 -> rows ty, ty+16, ty+32 (+ty+48 if ty<2)
template <bool FUSED_SCORES>
__device__ __forceinline__ void mm_AxW_v(const float* __restrict__ A,
                                         const float* __restrict__ W,
                                         const float* __restrict__ bias,
                                         float* __restrict__ C,
                                         const float* __restrict__ av1,
                                         const float* __restrict__ av2,
                                         float* __restrict__ s1,
                                         float* __restrict__ s2,
                                         int tx, int ty)
{
    const int r0 = ty, r1 = ty + 16, r2 = ty + 32;
    const bool has3 = (ty < 2);
    const int r3 = has3 ? (ty + 48) : ty;
    const int c0 = tx * 8;
    float acc0[8], acc1[8], acc2[8], acc3[8];
    #pragma unroll
    for (int j = 0; j < 8; ++j) { acc0[j]=0.f; acc1[j]=0.f; acc2[j]=0.f; acc3[j]=0.f; }

    for (int k = 0; k < 128; k += 4) {
        const float4 va0 = *reinterpret_cast<const float4*>(&A[r0*SP + k]);
        const float4 va1 = *reinterpret_cast<const float4*>(&A[r1*SP + k]);
        const float4 va2 = *reinterpret_cast<const float4*>(&A[r2*SP + k]);
        const float4 va3 = *reinterpret_cast<const float4*>(&A[r3*SP + k]);
        const float* Wk = W + k*128 + c0;
        #define GSTEP(CMP, KK) { \
            const float4 w0 = *reinterpret_cast<const float4*>(Wk + KK*128); \
            const float4 w1 = *reinterpret_cast<const float4*>(Wk + KK*128 + 4); \
            const float wv[8] = {w0.x,w0.y,w0.z,w0.w,w1.x,w1.y,w1.z,w1.w}; \
            _Pragma("unroll") \
            for (int j = 0; j < 8; ++j) { \
                acc0[j] = fmaf(va0.CMP, wv[j], acc0[j]); \
                acc1[j] = fmaf(va1.CMP, wv[j], acc1[j]); \
                acc2[j] = fmaf(va2.CMP, wv[j], acc2[j]); \
                acc3[j] = fmaf(va3.CMP, wv[j], acc3[j]); } }
        GSTEP(x,0) GSTEP(y,1) GSTEP(z,2) GSTEP(w,3)
        #undef GSTEP
    }

    if (!FUSED_SCORES) {
        #pragma unroll
        for (int j = 0; j < 8; ++j) {
            const float bb = bias[c0 + j];
            C[r0*SP + c0 + j] = acc0[j] + bb;
            C[r1*SP + c0 + j] = acc1[j] + bb;
            C[r2*SP + c0 + j] = acc2[j] + bb;
            if (has3) C[r3*SP + c0 + j] = acc3[j] + bb;
        }
    } else {
        #pragma unroll
        for (int j = 0; j < 8; ++j) {
            C[r0*SP + c0 + j] = acc0[j];
            C[r1*SP + c0 + j] = acc1[j];
            C[r2*SP + c0 + j] = acc2[j];
            if (has3) C[r3*SP + c0 + j] = acc3[j];
        }
        const float4 a1lo = *reinterpret_cast<const float4*>(av1 + c0);
        const float4 a1hi = *reinterpret_cast<const float4*>(av1 + c0 + 4);
        const float4 a2lo = *reinterpret_cast<const float4*>(av2 + c0);
        const float4 a2hi = *reinterpret_cast<const float4*>(av2 + c0 + 4);
        const float w1v[8] = {a1lo.x,a1lo.y,a1lo.z,a1lo.w,a1hi.x,a1hi.y,a1hi.z,a1hi.w};
        const float w2v[8] = {a2lo.x,a2lo.y,a2lo.z,a2lo.w,a2hi.x,a2hi.y,a2hi.z,a2hi.w};
        float p10=0.f,p11=0.f,p12=0.f,p13=0.f,p20=0.f,p21=0.f,p22=0.f,p23=0.f;
        #pragma unroll
        for (int j = 0; j < 8; ++j) {
            p10 = fmaf(acc0[j], w1v[j], p10);  p20 = fmaf(acc0[j], w2v[j], p20);
            p11 = fmaf(acc1[j], w1v[j], p11);  p21 = fmaf(acc1[j], w2v[j], p21);
            p12 = fmaf(acc2[j], w1v[j], p12);  p22 = fmaf(acc2[j], w2v[j], p22);
            p13 = fmaf(acc3[j], w1v[j], p13);  p23 = fmaf(acc3[j], w2v[j], p23);
        }
        #pragma unroll
        for (int m = 1; m < 16; m <<= 1) {   // reduce across the 16 tx lanes
            p10 += __shfl_xor(p10, m);  p20 += __shfl_xor(p20, m);
            p11 += __shfl_xor(p11, m);  p21 += __shfl_xor(p21, m);
            p12 += __shfl_xor(p12, m);  p22 += __shfl_xor(p22, m);
            p13 += __shfl_xor(p13, m);  p23 += __shfl_xor(p23, m);
        }
        if (tx == 0) {
            s1[r0] = p10;  s2[r0] = p20;
            s1[r1] = p11;  s2[r1] = p21;
            s1[r2] = p12;  s2[r2] = p22;
            if (has3) { s1[r3] = p13;  s2[r3] = p23; }
        }
    }
}

__global__ __launch_bounds__(256, 2) void gnn_fused(
    const float* __restrict__ x,
    const float* __restrict__ W1, const float* __restrict__ b1,
    const float* __restrict__ W2, const float* __restrict__ b2,
    const float* __restrict__ Wg,
    const float* __restrict__ a1v, const float* __restrict__ a2v,
    const float* __restrict__ Wo1, const float* __restrict__ bo1,
    const float* __restrict__ Wo2, const float* __restrict__ bo2,
    float* __restrict__ out)
{
    __shared__ __align__(16) float nf[NA * SP];     // 26400 B
    __shared__ __align__(16) float hbuf[NA * SP];   // 26400 B
    __shared__ __align__(16) float pool[NA * ASP];  // 10400 B: curs -> attn -> hid2 (time-aliased)
    __shared__ float s1[NA], s2[NA];                // 400 B  (total 63.6 KB -> 2 blocks/CU)

    float* const curs = pool;   // [50][6]
    float* const attn = pool;   // [50][ASP]
    float* const hid2 = pool;   // [512]

    const int tid = threadIdx.x;
    const int b = blockIdx.x;
    const int tx = tid & 15;
    const int ty = tid >> 4;
    const int r0 = ty, r1 = ty + 16, r2 = ty + 32;
    const bool has3 = (ty < 2);
    const int r3 = has3 ? (ty + 48) : ty;
    const int c0 = tx * 8;

    // ---- 1. load cur = x[b, :, T-1, :] (300 of 33000 floats) ----
    for (int idx = tid; idx < NA * 6; idx += 256) {
        const int a = idx / 6;
        const int f = idx - a * 6;
        curs[idx] = x[(size_t)b * 33000 + a * 660 + 109 * 6 + f];
    }
    __syncthreads();

    // ---- 2. hidden = relu(cur @ W1 + b1) -> hbuf ----
    for (int idx = tid; idx < NA * 128; idx += 256) {
        const int i = idx >> 7;
        const int j = idx & 127;
        float acc = b1[j];
        #pragma unroll
        for (int k = 0; k < 6; ++k) acc = fmaf(curs[i*6 + k], W1[k*128 + j], acc);
        hbuf[i*SP + j] = fmaxf(acc, 0.f);
    }
    __syncthreads();

    // ---- 3. nf = hidden @ W2 + b2 ----
    mm_AxW_v<false>(hbuf, W2, b2, nf, nullptr, nullptr, nullptr, nullptr, tx, ty);
    __syncthreads();

    // ---- 4. three GAT layers ----
    for (int l = 0; l < 3; ++l) {
        // h = nf @ Wg[l]; s1/s2 fused into the epilogue (no separate phase)
        mm_AxW_v<true>(nf, Wg + l*128*128, nullptr, hbuf,
                       a1v + l*128, a2v + l*128, s1, s2, tx, ty);
        __syncthreads();

        // softmax over leaky_relu(s1[i]+s2[j]), diag masked; 4 lanes per row
        {
            const int row = tid >> 2;
            const int g = tid & 3;
            const bool active = (row < NA) && (l < 2 || row == 0);
            float pv[13];
            float m = -1e30f;
            if (active) {
                const float si = s1[row];
                #pragma unroll
                for (int jj = 0; jj < 13; ++jj) {
                    const int j = g + jj*4;
                    float e = -1e30f;
                    if (j < NA && j != row) {
                        const float v = si + s2[j];
                        e = (v > 0.f) ? v : 0.2f * v;
                    }
                    pv[jj] = e;
                    m = fmaxf(m, e);
                }
            }
            m = fmaxf(m, __shfl_xor(m, 1));
            m = fmaxf(m, __shfl_xor(m, 2));
            float ssum = 0.f;
            if (active) {
                #pragma unroll
                for (int jj = 0; jj < 13; ++jj) {
                    const int j = g + jj*4;
                    const float p = (j < NA && j != row) ? __expf(pv[jj] - m) : 0.f;
                    pv[jj] = p;
                    ssum += p;
                }
            }
            ssum += __shfl_xor(ssum, 1);
            ssum += __shfl_xor(ssum, 2);
            if (active) {
                const float inv = 1.f / ssum;
                #pragma unroll
                for (int jj = 0; jj < 13; ++jj) {
                    const int j = g + jj*4;
                    if (j < NA) attn[row*ASP + j] = pv[jj] * inv;
                }
            }
        }
        __syncthreads();

        // nf = attn @ h (K=50, LDS); last layer computes row 0 only
        if (l < 2) {
            float acc0[8], acc1[8], acc2[8], acc3[8];
            #pragma unroll
            for (int j = 0; j < 8; ++j) { acc0[j]=0.f; acc1[j]=0.f; acc2[j]=0.f; acc3[j]=0.f; }
            for (int k = 0; k < 48; k += 4) {
                const float4 at0 = *reinterpret_cast<const float4*>(&attn[r0*ASP + k]);
                const float4 at1 = *reinterpret_cast<const float4*>(&attn[r1*ASP + k]);
                const float4 at2 = *reinterpret_cast<const float4*>(&attn[r2*ASP + k]);
                const float4 at3 = *reinterpret_cast<const float4*>(&attn[r3*ASP + k]);
                #define ASTEP(CMP, KK) { \
                    const float* Hk = &hbuf[(k+KK)*SP + c0]; \
                    const float4 h0 = *reinterpret_cast<const float4*>(Hk); \
                    const float4 h1 = *reinterpret_cast<const float4*>(Hk + 4); \
                    const float hv[8] = {h0.x,h0.y,h0.z,h0.w,h1.x,h1.y,h1.z,h1.w}; \
                    _Pragma("unroll") \
                    for (int j = 0; j < 8; ++j) { \
                        acc0[j] = fmaf(at0.CMP, hv[j], acc0[j]); \
                        acc1[j] = fmaf(at1.CMP, hv[j], acc1[j]); \
                        acc2[j] = fmaf(at2.CMP, hv[j], acc2[j]); \
                        acc3[j] = fmaf(at3.CMP, hv[j], acc3[j]); } }
                ASTEP(x,0) ASTEP(y,1) ASTEP(z,2) ASTEP(w,3)
                #undef ASTEP
            }
            #pragma unroll
            for (int k = 48; k < 50; ++k) {  // K tail
                const float at0 = attn[r0*ASP + k];
                const float at1 = attn[r1*ASP + k];
                const float at2 = attn[r2*ASP + k];
                const float at3 = attn[r3*ASP + k];
                const float* Hk = &hbuf[k*SP + c0];
                const float4 h0 = *reinterpret_cast<const float4*>(Hk);
                const float4 h1 = *reinterpret_cast<const float4*>(Hk + 4);
                const float hv[8] = {h0.x,h0.y,h0.z,h0.w,h1.x,h1.y,h1.z,h1.w};
                #pragma unroll
                for (int j = 0; j < 8; ++j) {
                    acc0[j] = fmaf(at0, hv[j], acc0[j]);
                    acc1[j] = fmaf(at1, hv[j], acc1[j]);
                    acc2[j] = fmaf(at2, hv[j], acc2[j]);
                    acc3[j] = fmaf(at3, hv[j], acc3[j]);
                }
            }
            // nf writes race nothing: hbuf/attn are the only concurrent reads
            #pragma unroll
            for (int j = 0; j < 8; ++j) {
                nf[r0*SP + c0 + j] = acc0[j];
                nf[r1*SP + c0 + j] = acc1[j];
                nf[r2*SP + c0 + j] = acc2[j];
                if (has3) nf[r3*SP + c0 + j] = acc3[j];
            }
        } else if (ty == 0) {   // last layer: only ego row 0
            float acc[8];
            #pragma unroll
            for (int j = 0; j < 8; ++j) acc[j] = 0.f;
            for (int k = 0; k < 48; k += 4) {
                const float4 at = *reinterpret_cast<const float4*>(&attn[k]);
                #define ESTEP(CMP, KK) { \
                    const float* Hk = &hbuf[(k+KK)*SP + c0]; \
                    const float4 h0 = *reinterpret_cast<const float4*>(Hk); \
                    const float4 h1 = *reinterpret_cast<const float4*>(Hk + 4); \
                    const float hv[8] = {h0.x,h0.y,h0.z,h0.w,h1.x,h1.y,h1.z,h1.w}; \
                    _Pragma("unroll") \
                    for (int j = 0; j < 8; ++j) acc[j] = fmaf(at.CMP, hv[j], acc[j]); }
                ESTEP(x,0) ESTEP(y,1) ESTEP(z,2) ESTEP(w,3)
                #undef ESTEP
            }
            #pragma unroll
            for (int k = 48; k < 50; ++k) {
                const float at = attn[k];
                const float* Hk = &hbuf[k*SP + c0];
                const float4 h0 = *reinterpret_cast<const float4*>(Hk);
                const float4 h1 = *reinterpret_cast<const float4*>(Hk + 4);
                const float hv[8] = {h0.x,h0.y,h0.z,h0.w,h1.x,h1.y,h1.z,h1.w};
                #pragma unroll
                for (int j = 0; j < 8; ++j) acc[j] = fmaf(at, hv[j], acc[j]);
            }
            #pragma unroll
            for (int j = 0; j < 8; ++j) nf[c0 + j] = acc[j];
        }
        __syncthreads();
    }

    // ---- 5. output MLP on ego = nf[0][0..127] ----
    float h2[2];
    #pragma unroll
    for (int u = 0; u < 2; ++u) {
        const int o = tid + u * 256;
        float pA = bo1[o], pB = 0.f, pC = 0.f, pD = 0.f;   // 4 ILP chains
        for (int k = 0; k < 128; k += 4) {
            const float4 nf4 = *reinterpret_cast<const float4*>(&nf[k]);
            pA = fmaf(nf4.x, Wo1[(k  )*512 + o], pA);
            pB = fmaf(nf4.y, Wo1[(k+1)*512 + o], pB);
            pC = fmaf(nf4.z, Wo1[(k+2)*512 + o], pC);
            pD = fmaf(nf4.w, Wo1[(k+3)*512 + o], pD);
        }
        h2[u] = fmaxf((pA + pB) + (pC + pD), 0.f);
    }
    __syncthreads();   // attn pool fully consumed; reuse as hid2
    hid2[tid] = h2[0];
    hid2[tid + 256] = h2[1];
    __syncthreads();

    if (tid < 120) {
        float pA = bo2[tid], pB = 0.f, pC = 0.f, pD = 0.f;
        for (int o = 0; o < 512; o += 4) {
            const float4 hv = *reinterpret_cast<const float4*>(&hid2[o]);
            pA = fmaf(hv.x, Wo2[(o  )*120 + tid], pA);
            pB = fmaf(hv.y, Wo2[(o+1)*120 + tid], pB);
            pC = fmaf(hv.z, Wo2[(o+2)*120 + tid], pC);
            pD = fmaf(hv.w, Wo2[(o+3)*120 + tid], pD);
        }
        out[b * 120 + tid] = (pA + pB) + (pC + pD);
    }
}

extern "C" void kernel_launch(void* const* d_in, const int* in_sizes, int n_in,
                              void* d_out, int out_size, void* d_ws, size_t ws_size,
                              hipStream_t stream) {
    const float* x   = (const float*)d_in[0];
    const float* W1  = (const float*)d_in[1];
    const float* b1  = (const float*)d_in[2];
    const float* W2  = (const float*)d_in[3];
    const float* b2  = (const float*)d_in[4];
    // d_in[5..8] = We1, be1, We2, be2 : dead code in the reference — unused
    const float* Wg  = (const float*)d_in[9];
    const float* a1  = (const float*)d_in[10];
    const float* a2  = (const float*)d_in[11];
    const float* Wo1 = (const float*)d_in[12];
    const float* bo1 = (const float*)d_in[13];
    const float* Wo2 = (const float*)d_in[14];
    const float* bo2 = (const float*)d_in[15];

    const int B = in_sizes[0] / (50 * 110 * 6);   // 1024
    gnn_fused<<<B, 256, 0, stream>>>(x, W1, b1, W2, b2, Wg, a1, a2,
                                     Wo1, bo1, Wo2, bo2, (float*)d_out);
}

// Round 10
// 392.840 us; speedup vs baseline: 1.2345x; 1.0255x over previous
//
#include <hip/hip_runtime.h>

#define NA 50     // agents
#define SP 132    // padded LDS row stride, %4==0 so float4 LDS loads stay 16B-aligned
#define ASP 52    // attention row stride, %4==0

// acc(4 rows x 8 cols) += A(50x128, LDS) @ W(128x128, global), accumulators stay in
// registers so the caller can barrier and write the output OVER the input buffer.
// Thread map: tx=tid&15 -> cols tx*8..+7; ty=tid>>4 -> rows ty, ty+16, ty+32 (+ty+48 if ty<2)
__device__ __forceinline__ void gemm_acc(const float* __restrict__ A,
                                         const float* __restrict__ W,
                                         int tx, int ty,
                                         float acc0[8], float acc1[8],
                                         float acc2[8], float acc3[8])
{
    const int r0 = ty, r1 = ty + 16, r2 = ty + 32;
    const int r3 = (ty < 2) ? (ty + 48) : ty;   // safe duplicate read when absent
    const int c0 = tx * 8;
    #pragma unroll
    for (int j = 0; j < 8; ++j) { acc0[j]=0.f; acc1[j]=0.f; acc2[j]=0.f; acc3[j]=0.f; }

    for (int k = 0; k < 128; k += 4) {
        const float4 va0 = *reinterpret_cast<const float4*>(&A[r0*SP + k]);
        const float4 va1 = *reinterpret_cast<const float4*>(&A[r1*SP + k]);
        const float4 va2 = *reinterpret_cast<const float4*>(&A[r2*SP + k]);
        const float4 va3 = *reinterpret_cast<const float4*>(&A[r3*SP + k]);
        const float* Wk = W + k*128 + c0;
        #define GSTEP(CMP, KK) { \
            const float4 w0 = *reinterpret_cast<const float4*>(Wk + KK*128); \
            const float4 w1 = *reinterpret_cast<const float4*>(Wk + KK*128 + 4); \
            const float wv[8] = {w0.x,w0.y,w0.z,w0.w,w1.x,w1.y,w1.z,w1.w}; \
            _Pragma("unroll") \
            for (int j = 0; j < 8; ++j) { \
                acc0[j] = fmaf(va0.CMP, wv[j], acc0[j]); \
                acc1[j] = fmaf(va1.CMP, wv[j], acc1[j]); \
                acc2[j] = fmaf(va2.CMP, wv[j], acc2[j]); \
                acc3[j] = fmaf(va3.CMP, wv[j], acc3[j]); } }
        GSTEP(x,0) GSTEP(y,1) GSTEP(z,2) GSTEP(w,3)
        #undef GSTEP
    }
}

__global__ __launch_bounds__(256, 4) void gnn_fused(
    const float* __restrict__ x,
    const float* __restrict__ W1, const float* __restrict__ b1,
    const float* __restrict__ W2, const float* __restrict__ b2,
    const float* __restrict__ Wg,
    const float* __restrict__ a1v, const float* __restrict__ a2v,
    const float* __restrict__ Wo1, const float* __restrict__ bo1,
    const float* __restrict__ Wo2, const float* __restrict__ bo2,
    float* __restrict__ out)
{
    // Single feature buffer: hidden -> nf -> h -> nf' ... (in-place via reg-staged GEMMs)
    __shared__ __align__(16) float buf[NA * SP];    // 26400 B
    __shared__ __align__(16) float pool[NA * ASP];  // 10400 B: curs -> attn -> hid2
    __shared__ float s1[NA], s2[NA];                // 400 B   (total 37.2 KB -> 4 blocks/CU)

    float* const curs = pool;   // [50][6]
    float* const attn = pool;   // [50][ASP]
    float* const hid2 = pool;   // [512]

    const int tid = threadIdx.x;
    const int b = blockIdx.x;
    const int tx = tid & 15;
    const int ty = tid >> 4;
    const int r0 = ty, r1 = ty + 16, r2 = ty + 32;
    const bool has3 = (ty < 2);
    const int r3 = has3 ? (ty + 48) : ty;
    const int c0 = tx * 8;

    float acc0[8], acc1[8], acc2[8], acc3[8];

    // ---- 1. load cur = x[b, :, T-1, :] (300 of 33000 floats) ----
    for (int idx = tid; idx < NA * 6; idx += 256) {
        const int a = idx / 6;
        const int f = idx - a * 6;
        curs[idx] = x[(size_t)b * 33000 + a * 660 + 109 * 6 + f];
    }
    __syncthreads();

    // ---- 2. hidden = relu(cur @ W1 + b1) -> buf ----
    for (int idx = tid; idx < NA * 128; idx += 256) {
        const int i = idx >> 7;
        const int j = idx & 127;
        float acc = b1[j];
        #pragma unroll
        for (int k = 0; k < 6; ++k) acc = fmaf(curs[i*6 + k], W1[k*128 + j], acc);
        buf[i*SP + j] = fmaxf(acc, 0.f);
    }
    __syncthreads();

    // ---- 3. nf = hidden @ W2 + b2 (in place: read all, barrier, write back) ----
    gemm_acc(buf, W2, tx, ty, acc0, acc1, acc2, acc3);
    __syncthreads();
    {
        #pragma unroll
        for (int j = 0; j < 8; ++j) {
            const float bb = b2[c0 + j];
            buf[r0*SP + c0 + j] = acc0[j] + bb;
            buf[r1*SP + c0 + j] = acc1[j] + bb;
            buf[r2*SP + c0 + j] = acc2[j] + bb;
            if (has3) buf[r3*SP + c0 + j] = acc3[j] + bb;
        }
    }
    __syncthreads();

    // ---- 4. three GAT layers ----
    for (int l = 0; l < 3; ++l) {
        // h = nf @ Wg[l]  (regs) ... then overwrite buf with h
        gemm_acc(buf, Wg + l*128*128, tx, ty, acc0, acc1, acc2, acc3);
        __syncthreads();
        {
            #pragma unroll
            for (int j = 0; j < 8; ++j) {
                buf[r0*SP + c0 + j] = acc0[j];
                buf[r1*SP + c0 + j] = acc1[j];
                buf[r2*SP + c0 + j] = acc2[j];
                if (has3) buf[r3*SP + c0 + j] = acc3[j];
            }
            // fused scores: s1[r]=h_row·a1, s2[r]=h_row·a2 via 16-lane shfl reduce
            const float* av1 = a1v + l*128;
            const float* av2 = a2v + l*128;
            const float4 a1lo = *reinterpret_cast<const float4*>(av1 + c0);
            const float4 a1hi = *reinterpret_cast<const float4*>(av1 + c0 + 4);
            const float4 a2lo = *reinterpret_cast<const float4*>(av2 + c0);
            const float4 a2hi = *reinterpret_cast<const float4*>(av2 + c0 + 4);
            const float w1v[8] = {a1lo.x,a1lo.y,a1lo.z,a1lo.w,a1hi.x,a1hi.y,a1hi.z,a1hi.w};
            const float w2v[8] = {a2lo.x,a2lo.y,a2lo.z,a2lo.w,a2hi.x,a2hi.y,a2hi.z,a2hi.w};
            float p10=0.f,p11=0.f,p12=0.f,p13=0.f,p20=0.f,p21=0.f,p22=0.f,p23=0.f;
            #pragma unroll
            for (int j = 0; j < 8; ++j) {
                p10 = fmaf(acc0[j], w1v[j], p10);  p20 = fmaf(acc0[j], w2v[j], p20);
                p11 = fmaf(acc1[j], w1v[j], p11);  p21 = fmaf(acc1[j], w2v[j], p21);
                p12 = fmaf(acc2[j], w1v[j], p12);  p22 = fmaf(acc2[j], w2v[j], p22);
                p13 = fmaf(acc3[j], w1v[j], p13);  p23 = fmaf(acc3[j], w2v[j], p23);
            }
            #pragma unroll
            for (int m = 1; m < 16; m <<= 1) {
                p10 += __shfl_xor(p10, m);  p20 += __shfl_xor(p20, m);
                p11 += __shfl_xor(p11, m);  p21 += __shfl_xor(p21, m);
                p12 += __shfl_xor(p12, m);  p22 += __shfl_xor(p22, m);
                p13 += __shfl_xor(p13, m);  p23 += __shfl_xor(p23, m);
            }
            if (tx == 0) {
                s1[r0] = p10;  s2[r0] = p20;
                s1[r1] = p11;  s2[r1] = p21;
                s1[r2] = p12;  s2[r2] = p22;
                if (has3) { s1[r3] = p13;  s2[r3] = p23; }
            }
        }
        __syncthreads();

        // softmax over leaky_relu(s1[i]+s2[j]), diag masked; 4 lanes per row
        {
            const int row = tid >> 2;
            const int g = tid & 3;
            const bool active = (row < NA) && (l < 2 || row == 0);
            float pv[13];
            float m = -1e30f;
            if (active) {
                const float si = s1[row];
                #pragma unroll
                for (int jj = 0; jj < 13; ++jj) {
                    const int j = g + jj*4;
                    float e = -1e30f;
                    if (j < NA && j != row) {
                        const float v = si + s2[j];
                        e = (v > 0.f) ? v : 0.2f * v;
                    }
                    pv[jj] = e;
                    m = fmaxf(m, e);
                }
            }
            m = fmaxf(m, __shfl_xor(m, 1));
            m = fmaxf(m, __shfl_xor(m, 2));
            float ssum = 0.f;
            if (active) {
                #pragma unroll
                for (int jj = 0; jj < 13; ++jj) {
                    const int j = g + jj*4;
                    const float p = (j < NA && j != row) ? __expf(pv[jj] - m) : 0.f;
                    pv[jj] = p;
                    ssum += p;
                }
            }
            ssum += __shfl_xor(ssum, 1);
            ssum += __shfl_xor(ssum, 2);
            if (active) {
                const float inv = 1.f / ssum;
                #pragma unroll
                for (int jj = 0; jj < 13; ++jj) {
                    const int j = g + jj*4;
                    if (j < NA) attn[row*ASP + j] = pv[jj] * inv;
                }
            }
        }
        __syncthreads();

        // nf' = attn @ h (K=50, h in buf) -> regs; last layer: row 0 only
        if (l < 2) {
            #pragma unroll
            for (int j = 0; j < 8; ++j) { acc0[j]=0.f; acc1[j]=0.f; acc2[j]=0.f; acc3[j]=0.f; }
            for (int k = 0; k < 48; k += 4) {
                const float4 at0 = *reinterpret_cast<const float4*>(&attn[r0*ASP + k]);
                const float4 at1 = *reinterpret_cast<const float4*>(&attn[r1*ASP + k]);
                const float4 at2 = *reinterpret_cast<const float4*>(&attn[r2*ASP + k]);
                const float4 at3 = *reinterpret_cast<const float4*>(&attn[r3*ASP + k]);
                #define ASTEP(CMP, KK) { \
                    const float* Hk = &buf[(k+KK)*SP + c0]; \
                    const float4 h0 = *reinterpret_cast<const float4*>(Hk); \
                    const float4 h1 = *reinterpret_cast<const float4*>(Hk + 4); \
                    const float hv[8] = {h0.x,h0.y,h0.z,h0.w,h1.x,h1.y,h1.z,h1.w}; \
                    _Pragma("unroll") \
                    for (int j = 0; j < 8; ++j) { \
                        acc0[j] = fmaf(at0.CMP, hv[j], acc0[j]); \
                        acc1[j] = fmaf(at1.CMP, hv[j], acc1[j]); \
                        acc2[j] = fmaf(at2.CMP, hv[j], acc2[j]); \
                        acc3[j] = fmaf(at3.CMP, hv[j], acc3[j]); } }
                ASTEP(x,0) ASTEP(y,1) ASTEP(z,2) ASTEP(w,3)
                #undef ASTEP
            }
            #pragma unroll
            for (int k = 48; k < 50; ++k) {  // K tail
                const float at0 = attn[r0*ASP + k];
                const float at1 = attn[r1*ASP + k];
                const float at2 = attn[r2*ASP + k];
                const float at3 = attn[r3*ASP + k];
                const float* Hk = &buf[k*SP + c0];
                const float4 h0 = *reinterpret_cast<const float4*>(Hk);
                const float4 h1 = *reinterpret_cast<const float4*>(Hk + 4);
                const float hv[8] = {h0.x,h0.y,h0.z,h0.w,h1.x,h1.y,h1.z,h1.w};
                #pragma unroll
                for (int j = 0; j < 8; ++j) {
                    acc0[j] = fmaf(at0, hv[j], acc0[j]);
                    acc1[j] = fmaf(at1, hv[j], acc1[j]);
                    acc2[j] = fmaf(at2, hv[j], acc2[j]);
                    acc3[j] = fmaf(at3, hv[j], acc3[j]);
                }
            }
            __syncthreads();   // all h reads done; safe to overwrite buf
            #pragma unroll
            for (int j = 0; j < 8; ++j) {
                buf[r0*SP + c0 + j] = acc0[j];
                buf[r1*SP + c0 + j] = acc1[j];
                buf[r2*SP + c0 + j] = acc2[j];
                if (has3) buf[r3*SP + c0 + j] = acc3[j];
            }
        } else {   // last layer: only ego row 0 (16 threads), but all barrier
            float acc[8];
            #pragma unroll
            for (int j = 0; j < 8; ++j) acc[j] = 0.f;
            if (ty == 0) {
                for (int k = 0; k < 48; k += 4) {
                    const float4 at = *reinterpret_cast<const float4*>(&attn[k]);
                    #define ESTEP(CMP, KK) { \
                        const float* Hk = &buf[(k+KK)*SP + c0]; \
                        const float4 h0 = *reinterpret_cast<const float4*>(Hk); \
                        const float4 h1 = *reinterpret_cast<const float4*>(Hk + 4); \
                        const float hv[8] = {h0.x,h0.y,h0.z,h0.w,h1.x,h1.y,h1.z,h1.w}; \
                        _Pragma("unroll") \
                        for (int j = 0; j < 8; ++j) acc[j] = fmaf(at.CMP, hv[j], acc[j]); }
                    ESTEP(x,0) ESTEP(y,1) ESTEP(z,2) ESTEP(w,3)
                    #undef ESTEP
                }
                #pragma unroll
                for (int k = 48; k < 50; ++k) {
                    const float at = attn[k];
                    const float* Hk = &buf[k*SP + c0];
                    const float4 h0 = *reinterpret_cast<const float4*>(Hk);
                    const float4 h1 = *reinterpret_cast<const float4*>(Hk + 4);
                    const float hv[8] = {h0.x,h0.y,h0.z,h0.w,h1.x,h1.y,h1.z,h1.w};
                    #pragma unroll
                    for (int j = 0; j < 8; ++j) acc[j] = fmaf(at, hv[j], acc[j]);
                }
            }
            __syncthreads();
            if (ty == 0) {
                #pragma unroll
                for (int j = 0; j < 8; ++j) buf[c0 + j] = acc[j];
            }
        }
        __syncthreads();
    }

    // ---- 5. output MLP on ego = buf[0][0..127] ----
    float h2[2];
    #pragma unroll
    for (int u = 0; u < 2; ++u) {
        const int o = tid + u * 256;
        float pA = bo1[o], pB = 0.f, pC = 0.f, pD = 0.f;   // 4 ILP chains
        for (int k = 0; k < 128; k += 4) {
            const float4 nf4 = *reinterpret_cast<const float4*>(&buf[k]);
            pA = fmaf(nf4.x, Wo1[(k  )*512 + o], pA);
            pB = fmaf(nf4.y, Wo1[(k+1)*512 + o], pB);
            pC = fmaf(nf4.z, Wo1[(k+2)*512 + o], pC);
            pD = fmaf(nf4.w, Wo1[(k+3)*512 + o], pD);
        }
        h2[u] = fmaxf((pA + pB) + (pC + pD), 0.f);
    }
    __syncthreads();   // attn pool fully consumed; reuse as hid2
    hid2[tid] = h2[0];
    hid2[tid + 256] = h2[1];
    __syncthreads();

    if (tid < 120) {
        float pA = bo2[tid], pB = 0.f, pC = 0.f, pD = 0.f;
        for (int o = 0; o < 512; o += 4) {
            const float4 hv = *reinterpret_cast<const float4*>(&hid2[o]);
            pA = fmaf(hv.x, Wo2[(o  )*120 + tid], pA);
            pB = fmaf(hv.y, Wo2[(o+1)*120 + tid], pB);
            pC = fmaf(hv.z, Wo2[(o+2)*120 + tid], pC);
            pD = fmaf(hv.w, Wo2[(o+3)*120 + tid], pD);
        }
        out[b * 120 + tid] = (pA + pB) + (pC + pD);
    }
}

extern "C" void kernel_launch(void* const* d_in, const int* in_sizes, int n_in,
                              void* d_out, int out_size, void* d_ws, size_t ws_size,
                              hipStream_t stream) {
    const float* x   = (const float*)d_in[0];
    const float* W1  = (const float*)d_in[1];
    const float* b1  = (const float*)d_in[2];
    const float* W2  = (const float*)d_in[3];
    const float* b2  = (const float*)d_in[4];
    // d_in[5..8] = We1, be1, We2, be2 : dead code in the reference — unused
    const float* Wg  = (const float*)d_in[9];
    const float* a1  = (const float*)d_in[10];
    const float* a2  = (const float*)d_in[11];
    const float* Wo1 = (const float*)d_in[12];
    const float* bo1 = (const float*)d_in[13];
    const float* Wo2 = (const float*)d_in[14];
    const float* bo2 = (const float*)d_in[15];

    const int B = in_sizes[0] / (50 * 110 * 6);   // 1024
    gnn_fused<<<B, 256, 0, stream>>>(x, W1, b1, W2, b2, Wg, a1, a2,
                                     Wo1, bo1, Wo2, bo2, (float*)d_out);
}

// Round 11
// 371.664 us; speedup vs baseline: 1.3049x; 1.0570x over previous
//
#include <hip/hip_runtime.h>

#define NA 50     // agents
#define SP 132    // padded LDS row stride, %4==0 so float4 LDS loads stay 16B-aligned
#define ASP 52    // attention row stride, %4==0

// acc(4 rows x 8 cols) += A(50x128, LDS) @ W(128x128, global), accumulators stay in
// registers so the caller can barrier and write the output OVER the input buffer.
// Thread map: tx=tid&15 -> cols tx*8..+7; ty=tid>>4 -> rows ty, ty+16, ty+32 (+ty+48 if ty<2)
__device__ __forceinline__ void gemm_acc(const float* __restrict__ A,
                                         const float* __restrict__ W,
                                         int tx, int ty,
                                         float acc0[8], float acc1[8],
                                         float acc2[8], float acc3[8])
{
    const int r0 = ty, r1 = ty + 16, r2 = ty + 32;
    const int r3 = (ty < 2) ? (ty + 48) : ty;   // safe duplicate read when absent
    const int c0 = tx * 8;
    #pragma unroll
    for (int j = 0; j < 8; ++j) { acc0[j]=0.f; acc1[j]=0.f; acc2[j]=0.f; acc3[j]=0.f; }

    for (int k = 0; k < 128; k += 4) {
        const float4 va0 = *reinterpret_cast<const float4*>(&A[r0*SP + k]);
        const float4 va1 = *reinterpret_cast<const float4*>(&A[r1*SP + k]);
        const float4 va2 = *reinterpret_cast<const float4*>(&A[r2*SP + k]);
        const float4 va3 = *reinterpret_cast<const float4*>(&A[r3*SP + k]);
        const float* Wk = W + k*128 + c0;
        #define GSTEP(CMP, KK) { \
            const float4 w0 = *reinterpret_cast<const float4*>(Wk + KK*128); \
            const float4 w1 = *reinterpret_cast<const float4*>(Wk + KK*128 + 4); \
            const float wv[8] = {w0.x,w0.y,w0.z,w0.w,w1.x,w1.y,w1.z,w1.w}; \
            _Pragma("unroll") \
            for (int j = 0; j < 8; ++j) { \
                acc0[j] = fmaf(va0.CMP, wv[j], acc0[j]); \
                acc1[j] = fmaf(va1.CMP, wv[j], acc1[j]); \
                acc2[j] = fmaf(va2.CMP, wv[j], acc2[j]); \
                acc3[j] = fmaf(va3.CMP, wv[j], acc3[j]); } }
        GSTEP(x,0) GSTEP(y,1) GSTEP(z,2) GSTEP(w,3)
        #undef GSTEP
    }
}

// launch_bounds(256,2): allows up to ~256 VGPR; measured allocation for this GEMM body
// is exactly 128 (round-6 profile) -> 4 waves/SIMD permitted by VGPR, and LDS (37.4 KB)
// permits 4 blocks/CU. (256,4) made the allocator target a 64-VGPR budget and spill
// 23 MB/dispatch to scratch (round-10 profile) — do NOT tighten this bound.
__global__ __launch_bounds__(256, 2) void gnn_fused(
    const float* __restrict__ x,
    const float* __restrict__ W1, const float* __restrict__ b1,
    const float* __restrict__ W2, const float* __restrict__ b2,
    const float* __restrict__ Wg,
    const float* __restrict__ a1v, const float* __restrict__ a2v,
    const float* __restrict__ Wo1, const float* __restrict__ bo1,
    const float* __restrict__ Wo2, const float* __restrict__ bo2,
    float* __restrict__ out)
{
    // Single feature buffer: hidden -> nf -> h -> nf' ... (in-place via reg-staged GEMMs)
    __shared__ __align__(16) float buf[NA * SP];    // 26400 B
    __shared__ __align__(16) float pool[NA * ASP];  // 10400 B: curs -> attn -> hid2
    __shared__ float s1[NA], s2[NA];                // 400 B   (total 37.2 KB -> 4 blocks/CU)

    float* const curs = pool;   // [50][6]
    float* const attn = pool;   // [50][ASP]
    float* const hid2 = pool;   // [512]

    const int tid = threadIdx.x;
    const int b = blockIdx.x;
    const int tx = tid & 15;
    const int ty = tid >> 4;
    const int r0 = ty, r1 = ty + 16, r2 = ty + 32;
    const bool has3 = (ty < 2);
    const int r3 = has3 ? (ty + 48) : ty;
    const int c0 = tx * 8;

    float acc0[8], acc1[8], acc2[8], acc3[8];

    // ---- 1. load cur = x[b, :, T-1, :] (300 of 33000 floats) ----
    for (int idx = tid; idx < NA * 6; idx += 256) {
        const int a = idx / 6;
        const int f = idx - a * 6;
        curs[idx] = x[(size_t)b * 33000 + a * 660 + 109 * 6 + f];
    }
    __syncthreads();

    // ---- 2. hidden = relu(cur @ W1 + b1) -> buf ----
    for (int idx = tid; idx < NA * 128; idx += 256) {
        const int i = idx >> 7;
        const int j = idx & 127;
        float acc = b1[j];
        #pragma unroll
        for (int k = 0; k < 6; ++k) acc = fmaf(curs[i*6 + k], W1[k*128 + j], acc);
        buf[i*SP + j] = fmaxf(acc, 0.f);
    }
    __syncthreads();

    // ---- 3. nf = hidden @ W2 + b2 (in place: read all, barrier, write back) ----
    gemm_acc(buf, W2, tx, ty, acc0, acc1, acc2, acc3);
    __syncthreads();
    {
        #pragma unroll
        for (int j = 0; j < 8; ++j) {
            const float bb = b2[c0 + j];
            buf[r0*SP + c0 + j] = acc0[j] + bb;
            buf[r1*SP + c0 + j] = acc1[j] + bb;
            buf[r2*SP + c0 + j] = acc2[j] + bb;
            if (has3) buf[r3*SP + c0 + j] = acc3[j] + bb;
        }
    }
    __syncthreads();

    // ---- 4. three GAT layers ----
    for (int l = 0; l < 3; ++l) {
        // h = nf @ Wg[l]  (regs) ... then overwrite buf with h
        gemm_acc(buf, Wg + l*128*128, tx, ty, acc0, acc1, acc2, acc3);
        __syncthreads();
        {
            #pragma unroll
            for (int j = 0; j < 8; ++j) {
                buf[r0*SP + c0 + j] = acc0[j];
                buf[r1*SP + c0 + j] = acc1[j];
                buf[r2*SP + c0 + j] = acc2[j];
                if (has3) buf[r3*SP + c0 + j] = acc3[j];
            }
            // fused scores: s1[r]=h_row·a1, s2[r]=h_row·a2 via 16-lane shfl reduce
            const float* av1 = a1v + l*128;
            const float* av2 = a2v + l*128;
            const float4 a1lo = *reinterpret_cast<const float4*>(av1 + c0);
            const float4 a1hi = *reinterpret_cast<const float4*>(av1 + c0 + 4);
            const float4 a2lo = *reinterpret_cast<const float4*>(av2 + c0);
            const float4 a2hi = *reinterpret_cast<const float4*>(av2 + c0 + 4);
            const float w1v[8] = {a1lo.x,a1lo.y,a1lo.z,a1lo.w,a1hi.x,a1hi.y,a1hi.z,a1hi.w};
            const float w2v[8] = {a2lo.x,a2lo.y,a2lo.z,a2lo.w,a2hi.x,a2hi.y,a2hi.z,a2hi.w};
            float p10=0.f,p11=0.f,p12=0.f,p13=0.f,p20=0.f,p21=0.f,p22=0.f,p23=0.f;
            #pragma unroll
            for (int j = 0; j < 8; ++j) {
                p10 = fmaf(acc0[j], w1v[j], p10);  p20 = fmaf(acc0[j], w2v[j], p20);
                p11 = fmaf(acc1[j], w1v[j], p11);  p21 = fmaf(acc1[j], w2v[j], p21);
                p12 = fmaf(acc2[j], w1v[j], p12);  p22 = fmaf(acc2[j], w2v[j], p22);
                p13 = fmaf(acc3[j], w1v[j], p13);  p23 = fmaf(acc3[j], w2v[j], p23);
            }
            #pragma unroll
            for (int m = 1; m < 16; m <<= 1) {
                p10 += __shfl_xor(p10, m);  p20 += __shfl_xor(p20, m);
                p11 += __shfl_xor(p11, m);  p21 += __shfl_xor(p21, m);
                p12 += __shfl_xor(p12, m);  p22 += __shfl_xor(p22, m);
                p13 += __shfl_xor(p13, m);  p23 += __shfl_xor(p23, m);
            }
            if (tx == 0) {
                s1[r0] = p10;  s2[r0] = p20;
                s1[r1] = p11;  s2[r1] = p21;
                s1[r2] = p12;  s2[r2] = p22;
                if (has3) { s1[r3] = p13;  s2[r3] = p23; }
            }
        }
        __syncthreads();

        // softmax over leaky_relu(s1[i]+s2[j]), diag masked; 4 lanes per row
        {
            const int row = tid >> 2;
            const int g = tid & 3;
            const bool active = (row < NA) && (l < 2 || row == 0);
            float pv[13];
            float m = -1e30f;
            if (active) {
                const float si = s1[row];
                #pragma unroll
                for (int jj = 0; jj < 13; ++jj) {
                    const int j = g + jj*4;
                    float e = -1e30f;
                    if (j < NA && j != row) {
                        const float v = si + s2[j];
                        e = (v > 0.f) ? v : 0.2f * v;
                    }
                    pv[jj] = e;
                    m = fmaxf(m, e);
                }
            }
            m = fmaxf(m, __shfl_xor(m, 1));
            m = fmaxf(m, __shfl_xor(m, 2));
            float ssum = 0.f;
            if (active) {
                #pragma unroll
                for (int jj = 0; jj < 13; ++jj) {
                    const int j = g + jj*4;
                    const float p = (j < NA && j != row) ? __expf(pv[jj] - m) : 0.f;
                    pv[jj] = p;
                    ssum += p;
                }
            }
            ssum += __shfl_xor(ssum, 1);
            ssum += __shfl_xor(ssum, 2);
            if (active) {
                const float inv = 1.f / ssum;
                #pragma unroll
                for (int jj = 0; jj < 13; ++jj) {
                    const int j = g + jj*4;
                    if (j < NA) attn[row*ASP + j] = pv[jj] * inv;
                }
            }
        }
        __syncthreads();

        // nf' = attn @ h (K=50, h in buf) -> regs; last layer: row 0 only
        if (l < 2) {
            #pragma unroll
            for (int j = 0; j < 8; ++j) { acc0[j]=0.f; acc1[j]=0.f; acc2[j]=0.f; acc3[j]=0.f; }
            for (int k = 0; k < 48; k += 4) {
                const float4 at0 = *reinterpret_cast<const float4*>(&attn[r0*ASP + k]);
                const float4 at1 = *reinterpret_cast<const float4*>(&attn[r1*ASP + k]);
                const float4 at2 = *reinterpret_cast<const float4*>(&attn[r2*ASP + k]);
                const float4 at3 = *reinterpret_cast<const float4*>(&attn[r3*ASP + k]);
                #define ASTEP(CMP, KK) { \
                    const float* Hk = &buf[(k+KK)*SP + c0]; \
                    const float4 h0 = *reinterpret_cast<const float4*>(Hk); \
                    const float4 h1 = *reinterpret_cast<const float4*>(Hk + 4); \
                    const float hv[8] = {h0.x,h0.y,h0.z,h0.w,h1.x,h1.y,h1.z,h1.w}; \
                    _Pragma("unroll") \
                    for (int j = 0; j < 8; ++j) { \
                        acc0[j] = fmaf(at0.CMP, hv[j], acc0[j]); \
                        acc1[j] = fmaf(at1.CMP, hv[j], acc1[j]); \
                        acc2[j] = fmaf(at2.CMP, hv[j], acc2[j]); \
                        acc3[j] = fmaf(at3.CMP, hv[j], acc3[j]); } }
                ASTEP(x,0) ASTEP(y,1) ASTEP(z,2) ASTEP(w,3)
                #undef ASTEP
            }
            #pragma unroll
            for (int k = 48; k < 50; ++k) {  // K tail
                const float at0 = attn[r0*ASP + k];
                const float at1 = attn[r1*ASP + k];
                const float at2 = attn[r2*ASP + k];
                const float at3 = attn[r3*ASP + k];
                const float* Hk = &buf[k*SP + c0];
                const float4 h0 = *reinterpret_cast<const float4*>(Hk);
                const float4 h1 = *reinterpret_cast<const float4*>(Hk + 4);
                const float hv[8] = {h0.x,h0.y,h0.z,h0.w,h1.x,h1.y,h1.z,h1.w};
                #pragma unroll
                for (int j = 0; j < 8; ++j) {
                    acc0[j] = fmaf(at0, hv[j], acc0[j]);
                    acc1[j] = fmaf(at1, hv[j], acc1[j]);
                    acc2[j] = fmaf(at2, hv[j], acc2[j]);
                    acc3[j] = fmaf(at3, hv[j], acc3[j]);
                }
            }
            __syncthreads();   // all h reads done; safe to overwrite buf
            #pragma unroll
            for (int j = 0; j < 8; ++j) {
                buf[r0*SP + c0 + j] = acc0[j];
                buf[r1*SP + c0 + j] = acc1[j];
                buf[r2*SP + c0 + j] = acc2[j];
                if (has3) buf[r3*SP + c0 + j] = acc3[j];
            }
        } else {   // last layer: only ego row 0 (16 threads), but all barrier
            float acc[8];
            #pragma unroll
            for (int j = 0; j < 8; ++j) acc[j] = 0.f;
            if (ty == 0) {
                for (int k = 0; k < 48; k += 4) {
                    const float4 at = *reinterpret_cast<const float4*>(&attn[k]);
                    #define ESTEP(CMP, KK) { \
                        const float* Hk = &buf[(k+KK)*SP + c0]; \
                        const float4 h0 = *reinterpret_cast<const float4*>(Hk); \
                        const float4 h1 = *reinterpret_cast<const float4*>(Hk + 4); \
                        const float hv[8] = {h0.x,h0.y,h0.z,h0.w,h1.x,h1.y,h1.z,h1.w}; \
                        _Pragma("unroll") \
                        for (int j = 0; j < 8; ++j) acc[j] = fmaf(at.CMP, hv[j], acc[j]); }
                    ESTEP(x,0) ESTEP(y,1) ESTEP(z,2) ESTEP(w,3)
                    #undef ESTEP
                }
                #pragma unroll
                for (int k = 48; k < 50; ++k) {
                    const float at = attn[k];
                    const float* Hk = &buf[k*SP + c0];
                    const float4 h0 = *reinterpret_cast<const float4*>(Hk);
                    const float4 h1 = *reinterpret_cast<const float4*>(Hk + 4);
                    const float hv[8] = {h0.x,h0.y,h0.z,h0.w,h1.x,h1.y,h1.z,h1.w};
                    #pragma unroll
                    for (int j = 0; j < 8; ++j) acc[j] = fmaf(at, hv[j], acc[j]);
                }
            }
            __syncthreads();
            if (ty == 0) {
                #pragma unroll
                for (int j = 0; j < 8; ++j) buf[c0 + j] = acc[j];
            }
        }
        __syncthreads();
    }

    // ---- 5. output MLP on ego = buf[0][0..127] ----
    float h2[2];
    #pragma unroll
    for (int u = 0; u < 2; ++u) {
        const int o = tid + u * 256;
        float pA = bo1[o], pB = 0.f, pC = 0.f, pD = 0.f;   // 4 ILP chains
        for (int k = 0; k < 128; k += 4) {
            const float4 nf4 = *reinterpret_cast<const float4*>(&buf[k]);
            pA = fmaf(nf4.x, Wo1[(k  )*512 + o], pA);
            pB = fmaf(nf4.y, Wo1[(k+1)*512 + o], pB);
            pC = fmaf(nf4.z, Wo1[(k+2)*512 + o], pC);
            pD = fmaf(nf4.w, Wo1[(k+3)*512 + o], pD);
        }
        h2[u] = fmaxf((pA + pB) + (pC + pD), 0.f);
    }
    __syncthreads();   // attn pool fully consumed; reuse as hid2
    hid2[tid] = h2[0];
    hid2[tid + 256] = h2[1];
    __syncthreads();

    if (tid < 120) {
        float pA = bo2[tid], pB = 0.f, pC = 0.f, pD = 0.f;
        for (int o = 0; o < 512; o += 4) {
            const float4 hv = *reinterpret_cast<const float4*>(&hid2[o]);
            pA = fmaf(hv.x, Wo2[(o  )*120 + tid], pA);
            pB = fmaf(hv.y, Wo2[(o+1)*120 + tid], pB);
            pC = fmaf(hv.z, Wo2[(o+2)*120 + tid], pC);
            pD = fmaf(hv.w, Wo2[(o+3)*120 + tid], pD);
        }
        out[b * 120 + tid] = (pA + pB) + (pC + pD);
    }
}

extern "C" void kernel_launch(void* const* d_in, const int* in_sizes, int n_in,
                              void* d_out, int out_size, void* d_ws, size_t ws_size,
                              hipStream_t stream) {
    const float* x   = (const float*)d_in[0];
    const float* W1  = (const float*)d_in[1];
    const float* b1  = (const float*)d_in[2];
    const float* W2  = (const float*)d_in[3];
    const float* b2  = (const float*)d_in[4];
    // d_in[5..8] = We1, be1, We2, be2 : dead code in the reference — unused
    const float* Wg  = (const float*)d_in[9];
    const float* a1  = (const float*)d_in[10];
    const float* a2  = (const float*)d_in[11];
    const float* Wo1 = (const float*)d_in[12];
    const float* bo1 = (const float*)d_in[13];
    const float* Wo2 = (const float*)d_in[14];
    const float* bo2 = (const float*)d_in[15];

    const int B = in_sizes[0] / (50 * 110 * 6);   // 1024
    gnn_fused<<<B, 256, 0, stream>>>(x, W1, b1, W2, b2, Wg, a1, a2,
                                     Wo1, bo1, Wo2, bo2, (float*)d_out);
}

// Round 13
// 278.080 us; speedup vs baseline: 1.7440x; 1.3365x over previous
//
#include <hip/hip_runtime.h>

#define NA 50

// MFMA fragment types (per guide §3, compile-verified on gfx950: short8 carries bf16 bits)
typedef short bf16x8 __attribute__((ext_vector_type(8)));
typedef float f32x4  __attribute__((ext_vector_type(4)));

// LDS byte-offset map (single pool, 35984 B -> 4 blocks/CU)
// A_lds : bf16 nf/hidden [m<50][k=128], row stride 256B, swizzle ^((m&7)<<4)
//         (reads for pad rows 50..63 run off the end into attn region: garbage rows
//          feed only DISCARDED D rows -> safe)
// attn  : bf16 [q<50][k=64], row stride 128B, swizzle ^((q&7)<<4); k-cols 50..63 ZEROED once
// h_t   : bf16 h transposed [n=128][k=64], row stride 128B, swizzle ^((n&7)<<4);
//         k-rows 50..63 ZEROED once (0 x 0 pad pairs -> no NaN leakage)
#define A_OFF    0
#define ATTN_OFF 12800
#define HT_OFF   19200
#define CURS_OFF 19200   // overlay: cur[50][6] f32, dead before h_t first written
#define EGO_OFF  19200   // overlay: ego[128] f32, after h_t dead
#define HID2_OFF 19712   // overlay: hid2[512] f32
#define S1_OFF   35584
#define S2_OFF   35784
#define SMEM_BYTES 35984

__device__ __forceinline__ unsigned short f2bf(float f) {   // fp32 -> bf16 RNE
    unsigned u = __builtin_bit_cast(unsigned, f);
    u += 0x7fffu + ((u >> 16) & 1u);
    return (unsigned short)(u >> 16);
}
__device__ __forceinline__ unsigned pack2(float lo, float hi) {
    return (unsigned)f2bf(lo) | ((unsigned)f2bf(hi) << 16);
}

// Pre-kernel: convert W2 + Wg[0..2] (fp32, row-major [k][n]) into bf16 stored in exact
// B-fragment order for mfma_f32_16x16x32_bf16: elem((g,nt,kt,lane,i)) = W[kt*32+(lane>>4)*8+i][nt*16+(lane&15)]
// Main kernel then loads B-frags as coalesced 16B/lane. Runs every launch (d_ws is re-poisoned).
__global__ void prep_weights(const float* __restrict__ W2, const float* __restrict__ Wg,
                             unsigned short* __restrict__ wb)
{
    const int idx = blockIdx.x * 256 + threadIdx.x;     // 65536 total = 4 * 128*128
    const int g    = idx >> 14;
    const int e    = idx & 16383;
    const int i    = e & 7;
    const int lane = (e >> 3) & 63;
    const int kt   = (e >> 9) & 3;
    const int nt   = (e >> 11) & 7;
    const int k = kt * 32 + (lane >> 4) * 8 + i;
    const int n = nt * 16 + (lane & 15);
    const float* src = (g == 0) ? W2 : (Wg + (g - 1) * 16384);
    wb[idx] = f2bf(src[k * 128 + n]);
}

__global__ __launch_bounds__(256, 2) void gnn_fused(
    const float* __restrict__ x,
    const float* __restrict__ W1, const float* __restrict__ b1,
    const float* __restrict__ b2,
    const unsigned short* __restrict__ wb,
    const float* __restrict__ a1v, const float* __restrict__ a2v,
    const float* __restrict__ Wo1, const float* __restrict__ bo1,
    const float* __restrict__ Wo2, const float* __restrict__ bo2,
    float* __restrict__ out)
{
    __shared__ __align__(16) char smem[SMEM_BYTES];
    float* const s1 = (float*)(smem + S1_OFF);
    float* const s2 = (float*)(smem + S2_OFF);

    const int tid  = threadIdx.x;
    const int b    = blockIdx.x;
    const int lane = tid & 63;
    const int mt   = tid >> 6;        // wave id == M-tile (rows mt*16..mt*16+15)
    const int lr   = lane & 15;       // input frags: m/n index; D: n index
    const int lk   = lane >> 4;       // input frags: k-group;   D: row-group

    f32x4 acc[8];                     // one f32x4 per N-tile (always statically indexed)

    // ---- 1. cur = x[b,:,T-1,:] ----
    {
        float* curs = (float*)(smem + CURS_OFF);
        for (int idx = tid; idx < NA * 6; idx += 256) {
            const int a = idx / 6, f = idx - a * 6;
            curs[idx] = x[(size_t)b * 33000 + a * 660 + 654 + f];
        }
    }
    __syncthreads();

    // ---- 2. hidden = relu(cur@W1+b1) -> A_lds bf16 (paired writes) ----
    {
        const float* curs = (const float*)(smem + CURS_OFF);
        for (int idx = tid; idx < NA * 64; idx += 256) {
            const int i = idx >> 6, jp = idx & 63, j = jp * 2;
            float aL = b1[j], aH = b1[j + 1];
            #pragma unroll
            for (int k = 0; k < 6; ++k) {
                const float c = curs[i * 6 + k];
                aL = fmaf(c, W1[k * 128 + j],     aL);
                aH = fmaf(c, W1[k * 128 + j + 1], aH);
            }
            const int off = (i * 256 + jp * 4) ^ ((i & 7) << 4);
            *(unsigned*)(smem + A_OFF + off) = pack2(fmaxf(aL, 0.f), fmaxf(aH, 0.f));
        }
    }
    __syncthreads();

    // ---- 3. GEMM nf = hidden @ W2 (MFMA, in-place on A_lds) + zero attn/h_t pads ----
    {
        bf16x8 af[4];
        #pragma unroll
        for (int kt = 0; kt < 4; ++kt) {
            const int m = mt * 16 + lr;
            const int off = (m * 256 + (kt * 32 + lk * 8) * 2) ^ ((m & 7) << 4);
            af[kt] = *(const bf16x8*)(smem + A_OFF + off);
        }
        // zero attn (rows 0..49 incl. k-pad cols) + full h_t — curs is dead now
        for (int w = tid; w < (6400 + 16384) / 4; w += 256)
            *(unsigned*)(smem + ATTN_OFF + w * 4) = 0u;
        #pragma unroll
        for (int nt = 0; nt < 8; ++nt) {
            f32x4 a = {0.f, 0.f, 0.f, 0.f};
            #pragma unroll
            for (int kt = 0; kt < 4; ++kt) {
                const bf16x8 bf = *(const bf16x8*)(wb + ((nt * 4 + kt) * 64 + lane) * 8);
                a = __builtin_amdgcn_mfma_f32_16x16x32_bf16(af[kt], bf, a, 0, 0, 0);
            }
            acc[nt] = a;
        }
    }
    __syncthreads();                   // all A-frag reads done -> safe to overwrite A_lds
    {
        #pragma unroll
        for (int nt = 0; nt < 8; ++nt) {
            const int n = nt * 16 + lr;
            const float bb = b2[n];
            #pragma unroll
            for (int reg = 0; reg < 4; ++reg) {
                const int m = mt * 16 + lk * 4 + reg;   // D: row=(lane>>4)*4+reg [m89]
                if (m < NA) {
                    const int off = (m * 256 + n * 2) ^ ((m & 7) << 4);
                    *(unsigned short*)(smem + A_OFF + off) = f2bf(acc[nt][reg] + bb);
                }
            }
        }
    }
    __syncthreads();

    // ---- 4. three GAT layers (3 barriers each) ----
    for (int l = 0; l < 3; ++l) {
        // GEMM h = nf @ Wg[l] -> D-frags (fp32 regs)
        {
            bf16x8 af[4];
            #pragma unroll
            for (int kt = 0; kt < 4; ++kt) {
                const int m = mt * 16 + lr;
                const int off = (m * 256 + (kt * 32 + lk * 8) * 2) ^ ((m & 7) << 4);
                af[kt] = *(const bf16x8*)(smem + A_OFF + off);
            }
            const unsigned short* wg = wb + (l + 1) * 16384;
            #pragma unroll
            for (int nt = 0; nt < 8; ++nt) {
                f32x4 a = {0.f, 0.f, 0.f, 0.f};
                #pragma unroll
                for (int kt = 0; kt < 4; ++kt) {
                    const bf16x8 bf = *(const bf16x8*)(wg + ((nt * 4 + kt) * 64 + lane) * 8);
                    a = __builtin_amdgcn_mfma_f32_16x16x32_bf16(af[kt], bf, a, 0, 0, 0);
                }
                acc[nt] = a;
            }
        }
        // fused scores (fp32 from D-frags) + h_t bf16 transposed write
        {
            float p1[4] = {0.f, 0.f, 0.f, 0.f}, p2[4] = {0.f, 0.f, 0.f, 0.f};
            #pragma unroll
            for (int nt = 0; nt < 8; ++nt) {
                const int n = nt * 16 + lr;
                const float va1 = a1v[l * 128 + n], va2 = a2v[l * 128 + n];
                #pragma unroll
                for (int reg = 0; reg < 4; ++reg) {
                    p1[reg] = fmaf(acc[nt][reg], va1, p1[reg]);
                    p2[reg] = fmaf(acc[nt][reg], va2, p2[reg]);
                }
            }
            #pragma unroll
            for (int msk = 1; msk < 16; msk <<= 1) {
                #pragma unroll
                for (int reg = 0; reg < 4; ++reg) {
                    p1[reg] += __shfl_xor(p1[reg], msk);
                    p2[reg] += __shfl_xor(p2[reg], msk);
                }
            }
            if (lr == 0) {
                #pragma unroll
                for (int reg = 0; reg < 4; ++reg) {
                    const int m = mt * 16 + lk * 4 + reg;
                    if (m < NA) { s1[m] = p1[reg]; s2[m] = p2[reg]; }
                }
            }
            const int m0 = mt * 16 + lk * 4;      // 4 consecutive m per lane -> packed writes
            #pragma unroll
            for (int nt = 0; nt < 8; ++nt) {
                const int n = nt * 16 + lr;
                const int off = (n * 128 + m0 * 2) ^ ((n & 7) << 4);
                if (m0 + 3 < NA) {
                    *(unsigned*)(smem + HT_OFF + off)     = pack2(acc[nt][0], acc[nt][1]);
                    *(unsigned*)(smem + HT_OFF + off + 4) = pack2(acc[nt][2], acc[nt][3]);
                } else if (m0 < NA) {             // m0 == 48: keep k-pad 50..63 zero
                    *(unsigned*)(smem + HT_OFF + off)     = pack2(acc[nt][0], acc[nt][1]);
                }
            }
        }
        __syncthreads();

        // softmax (fp32) -> attn bf16 swizzled; diag = exact 0
        {
            const int row = tid >> 2;
            const int g = tid & 3;
            const bool active = (row < NA);
            float pv[13];
            float m = -1e30f;
            if (active) {
                const float si = s1[row];
                #pragma unroll
                for (int jj = 0; jj < 13; ++jj) {
                    const int j = g + jj * 4;
                    float e = -1e30f;
                    if (j < NA && j != row) {
                        const float v = si + s2[j];
                        e = (v > 0.f) ? v : 0.2f * v;
                    }
                    pv[jj] = e;
                    m = fmaxf(m, e);
                }
            }
            m = fmaxf(m, __shfl_xor(m, 1));
            m = fmaxf(m, __shfl_xor(m, 2));
            float ss = 0.f;
            if (active) {
                #pragma unroll
                for (int jj = 0; jj < 13; ++jj) {
                    const int j = g + jj * 4;
                    const float p = (j < NA && j != row) ? __expf(pv[jj] - m) : 0.f;
                    pv[jj] = p;
                    ss += p;
                }
            }
            ss += __shfl_xor(ss, 1);
            ss += __shfl_xor(ss, 2);
            if (active) {
                const float inv = 1.f / ss;
                #pragma unroll
                for (int jj = 0; jj < 13; ++jj) {
                    const int j = g + jj * 4;
                    if (j < NA) {
                        const int off = (row * 128 + j * 2) ^ ((row & 7) << 4);
                        *(unsigned short*)(smem + ATTN_OFF + off) = f2bf(pv[jj] * inv);
                    }
                }
            }
        }
        __syncthreads();

        // PV: nf' = attn @ h  (K padded to 64; pad pairs are 0x0)
        {
            bf16x8 paf[2];
            #pragma unroll
            for (int kt = 0; kt < 2; ++kt) {
                const int q = mt * 16 + lr;
                const int off = (q * 128 + (kt * 32 + lk * 8) * 2) ^ ((q & 7) << 4);
                paf[kt] = *(const bf16x8*)(smem + ATTN_OFF + off);
            }
            #pragma unroll
            for (int nt = 0; nt < 8; ++nt) {
                f32x4 a = {0.f, 0.f, 0.f, 0.f};
                #pragma unroll
                for (int kt = 0; kt < 2; ++kt) {
                    const int n = nt * 16 + lr;
                    const int off = (n * 128 + (kt * 32 + lk * 8) * 2) ^ ((n & 7) << 4);
                    const bf16x8 bf = *(const bf16x8*)(smem + HT_OFF + off);
                    a = __builtin_amdgcn_mfma_f32_16x16x32_bf16(paf[kt], bf, a, 0, 0, 0);
                }
                acc[nt] = a;
            }
        }
        if (l < 2) {
            // write nf' -> A_lds (A_lds last read was this layer's GEMM, already fenced)
            #pragma unroll
            for (int nt = 0; nt < 8; ++nt) {
                const int n = nt * 16 + lr;
                #pragma unroll
                for (int reg = 0; reg < 4; ++reg) {
                    const int m = mt * 16 + lk * 4 + reg;
                    if (m < NA) {
                        const int off = (m * 256 + n * 2) ^ ((m & 7) << 4);
                        *(unsigned short*)(smem + A_OFF + off) = f2bf(acc[nt][reg]);
                    }
                }
            }
            __syncthreads();
        } else {
            __syncthreads();   // drain all h_t reads before ego overwrites h_t region
            if (mt == 0 && lk == 0) {
                #pragma unroll
                for (int nt = 0; nt < 8; ++nt)
                    ((float*)(smem + EGO_OFF))[nt * 16 + lr] = acc[nt][0];   // row 0, fp32
            }
            __syncthreads();
        }
    }

    // ---- 5. output MLP on ego (fp32, unchanged structure) ----
    const float* ego  = (const float*)(smem + EGO_OFF);
    float*       hid2 = (float*)(smem + HID2_OFF);
    float h2[2];
    #pragma unroll
    for (int u = 0; u < 2; ++u) {
        const int o = tid + u * 256;
        float pA = bo1[o], pB = 0.f, pC = 0.f, pD = 0.f;
        for (int k = 0; k < 128; k += 4) {
            const float4 e4 = *(const float4*)(ego + k);
            pA = fmaf(e4.x, Wo1[(k    ) * 512 + o], pA);
            pB = fmaf(e4.y, Wo1[(k + 1) * 512 + o], pB);
            pC = fmaf(e4.z, Wo1[(k + 2) * 512 + o], pC);
            pD = fmaf(e4.w, Wo1[(k + 3) * 512 + o], pD);
        }
        h2[u] = fmaxf((pA + pB) + (pC + pD), 0.f);
    }
    __syncthreads();
    hid2[tid] = h2[0];
    hid2[tid + 256] = h2[1];
    __syncthreads();

    if (tid < 120) {
        float pA = bo2[tid], pB = 0.f, pC = 0.f, pD = 0.f;
        for (int o = 0; o < 512; o += 4) {
            const float4 hv = *(const float4*)(hid2 + o);
            pA = fmaf(hv.x, Wo2[(o    ) * 120 + tid], pA);
            pB = fmaf(hv.y, Wo2[(o + 1) * 120 + tid], pB);
            pC = fmaf(hv.z, Wo2[(o + 2) * 120 + tid], pC);
            pD = fmaf(hv.w, Wo2[(o + 3) * 120 + tid], pD);
        }
        out[b * 120 + tid] = (pA + pB) + (pC + pD);
    }
}

extern "C" void kernel_launch(void* const* d_in, const int* in_sizes, int n_in,
                              void* d_out, int out_size, void* d_ws, size_t ws_size,
                              hipStream_t stream) {
    const float* x   = (const float*)d_in[0];
    const float* W1  = (const float*)d_in[1];
    const float* b1  = (const float*)d_in[2];
    const float* W2  = (const float*)d_in[3];
    const float* b2  = (const float*)d_in[4];
    // d_in[5..8] = We1, be1, We2, be2 : dead code in the reference — unused
    const float* Wg  = (const float*)d_in[9];
    const float* a1  = (const float*)d_in[10];
    const float* a2  = (const float*)d_in[11];
    const float* Wo1 = (const float*)d_in[12];
    const float* bo1 = (const float*)d_in[13];
    const float* Wo2 = (const float*)d_in[14];
    const float* bo2 = (const float*)d_in[15];

    unsigned short* wb = (unsigned short*)d_ws;   // 4*16384 bf16 = 128 KB (ws re-poisoned; fully rewritten)
    prep_weights<<<256, 256, 0, stream>>>(W2, Wg, wb);

    const int B = in_sizes[0] / (50 * 110 * 6);   // 1024
    gnn_fused<<<B, 256, 0, stream>>>(x, W1, b1, b2, wb, a1, a2,
                                     Wo1, bo1, Wo2, bo2, (float*)d_out);
}